// Round 7
// baseline (161.809 us; speedup 1.0000x reference)
//
#include <hip/hip_runtime.h>

typedef _Float16 f16x8 __attribute__((ext_vector_type(8)));
typedef float    f32x4 __attribute__((ext_vector_type(4)));

#define N_ROWS 8192
#define DIM 64
#define EPS 1e-8f
#define LOG2E 1.4426950408889634f
#define SHIFT 96.0f                      // exp terms scaled by 2^96
#define SHIFT_LN 66.54212933375474f      // 96 * ln(2)
#define CH 128                           // chunk (block tile) size
#define NCH (N_ROWS / CH)                // 64
#define NPAIRS (NCH * (NCH + 1) / 2)     // 2080
#define NT (CH / 16)                     // 8 j-tiles per block

// ws: top[8192] | bot[8192] | sq[8192] (f32) | xh[8192*64] | xl[8192*64] (f16) | counter (int)

// prep: 4 threads per row, fully coalesced; fuses zeroing of top/bot/out/counter
__global__ __launch_bounds__(256) void snn_prep(
    const float* __restrict__ x, _Float16* __restrict__ xh,
    _Float16* __restrict__ xl, float* __restrict__ sq,
    float* __restrict__ top, float* __restrict__ bot,
    float* __restrict__ out, int* __restrict__ counter)
{
    const int tid = threadIdx.x;
    const int gt = blockIdx.x * 256 + tid;
    if (gt < N_ROWS) { top[gt] = 0.0f; bot[gt] = 0.0f; }
    if (gt == 0) { out[0] = 0.0f; counter[0] = 0; }

    const int row = blockIdx.x * 64 + (tid >> 2);
    const int seg = tid & 3;                      // 16 floats per segment
    const float4* xb = (const float4*)(x + row * DIM + seg * 16);
    float4 v0 = xb[0], v1 = xb[1], v2 = xb[2], v3 = xb[3];
    f16x8 h0, h1, l0, l1;
    float s = 0.0f;
#define CV(H, L, o, val) { float vv = (val); _Float16 hh = (_Float16)vv; \
                           H[o] = hh; L[o] = (_Float16)(vv - (float)hh); s += vv * vv; }
    CV(h0, l0, 0, v0.x) CV(h0, l0, 1, v0.y) CV(h0, l0, 2, v0.z) CV(h0, l0, 3, v0.w)
    CV(h0, l0, 4, v1.x) CV(h0, l0, 5, v1.y) CV(h0, l0, 6, v1.z) CV(h0, l0, 7, v1.w)
    CV(h1, l1, 0, v2.x) CV(h1, l1, 1, v2.y) CV(h1, l1, 2, v2.z) CV(h1, l1, 3, v2.w)
    CV(h1, l1, 4, v3.x) CV(h1, l1, 5, v3.y) CV(h1, l1, 6, v3.z) CV(h1, l1, 7, v3.w)
#undef CV
    *(f16x8*)(xh + row * DIM + seg * 16)     = h0;
    *(f16x8*)(xh + row * DIM + seg * 16 + 8) = h1;
    *(f16x8*)(xl + row * DIM + seg * 16)     = l0;
    *(f16x8*)(xl + row * DIM + seg * 16 + 8) = l1;
    s += __shfl_xor(s, 1, 64);
    s += __shfl_xor(s, 2, 64);
    if (seg == 0) sq[row] = s;
}

// symmetric pair-block kernel: chunk pairs (bi <= bj), 128x128 tile per block.
// Each e2 contributes to row i (registers) and, for bi<bj, to row j (LDS cols).
// Last block to finish performs the final log-reduction (arrival counter).
__global__ __launch_bounds__(256, 2) void snn_sym(
    const _Float16* __restrict__ xh, const _Float16* __restrict__ xl,
    const float* __restrict__ sq, const int* __restrict__ y,
    const float* __restrict__ w,
    float* __restrict__ top, float* __restrict__ bot,
    int* __restrict__ counter, float* __restrict__ out)
{
    __shared__ float s_sq[CH]; __shared__ int s_y[CH];
    __shared__ float s_ct[CH], s_cb[CH];
    __shared__ float s_red[4];
    __shared__ int s_last;

    // triangular decode (uniform scalar loop)
    int idx = blockIdx.x, bi = 0;
    while (idx >= NCH - bi) { idx -= NCH - bi; bi++; }
    const int bj = bi + idx;

    const int tid = threadIdx.x, wv = tid >> 6, lane = tid & 63;
    const int mrow = lane & 15, kq = lane >> 4;
    const int I0 = bi * CH + wv * 32;     // this wave's 32 i-rows
    const int j0 = bj * CH;

    if (tid < CH) {
        s_sq[tid] = sq[j0 + tid];
        s_y[tid]  = y[j0 + tid];
        s_ct[tid] = 0.0f; s_cb[tid] = 0.0f;
    }
    __syncthreads();

    // A fragments (2 m-tiles x 2 k-chunks, hi/lo planes) resident: 32 VGPRs
    f16x8 ah[2][2], al[2][2];
    #pragma unroll
    for (int mt = 0; mt < 2; mt++)
        #pragma unroll
        for (int kc = 0; kc < 2; kc++) {
            int a = (I0 + mt * 16 + mrow) * DIM + kc * 32 + kq * 8;
            ah[mt][kc] = *(const f16x8*)(xh + a);
            al[mt][kc] = *(const f16x8*)(xl + a);
        }

    float sqi[2][4]; int yi[2][4];
    #pragma unroll
    for (int mt = 0; mt < 2; mt++)
        #pragma unroll
        for (int r = 0; r < 4; r++) {
            int i = I0 + mt * 16 + kq * 4 + r;
            sqi[mt][r] = sq[i];
            yi[mt][r]  = y[i];
        }

    float ts[2][4], bs[2][4];
    #pragma unroll
    for (int mt = 0; mt < 2; mt++)
        #pragma unroll
        for (int r = 0; r < 4; r++) { ts[mt][r] = 0.0f; bs[mt][r] = 0.0f; }

    const float c1 = -w[0] * LOG2E;

#define MFMA_TILE                                                                          \
    const int jb = nt * 16;                                                                \
    const int bbase = (j0 + jb + mrow) * DIM + kq * 8;                                     \
    f16x8 bh0 = *(const f16x8*)(xh + bbase);                                               \
    f16x8 bh1 = *(const f16x8*)(xh + bbase + 32);                                          \
    f16x8 bl0 = *(const f16x8*)(xl + bbase);                                               \
    f16x8 bl1 = *(const f16x8*)(xl + bbase + 32);                                          \
    const float sqj = s_sq[jb + mrow];                                                     \
    const int   yj  = s_y[jb + mrow];                                                      \
    f32x4 acc[2];                                                                          \
    acc[0] = (f32x4){0.f, 0.f, 0.f, 0.f}; acc[1] = acc[0];                                 \
    _Pragma("unroll") for (int mt = 0; mt < 2; mt++)                                       \
        acc[mt] = __builtin_amdgcn_mfma_f32_16x16x32_f16(ah[mt][0], bh0, acc[mt], 0,0,0);  \
    _Pragma("unroll") for (int mt = 0; mt < 2; mt++)                                       \
        acc[mt] = __builtin_amdgcn_mfma_f32_16x16x32_f16(ah[mt][1], bh1, acc[mt], 0,0,0);  \
    _Pragma("unroll") for (int mt = 0; mt < 2; mt++)                                       \
        acc[mt] = __builtin_amdgcn_mfma_f32_16x16x32_f16(ah[mt][0], bl0, acc[mt], 0,0,0);  \
    _Pragma("unroll") for (int mt = 0; mt < 2; mt++)                                       \
        acc[mt] = __builtin_amdgcn_mfma_f32_16x16x32_f16(ah[mt][1], bl1, acc[mt], 0,0,0);  \
    _Pragma("unroll") for (int mt = 0; mt < 2; mt++)                                       \
        acc[mt] = __builtin_amdgcn_mfma_f32_16x16x32_f16(al[mt][0], bh0, acc[mt], 0,0,0);  \
    _Pragma("unroll") for (int mt = 0; mt < 2; mt++)                                       \
        acc[mt] = __builtin_amdgcn_mfma_f32_16x16x32_f16(al[mt][1], bh1, acc[mt], 0,0,0);

    if (bi == bj) {
        // diagonal chunk: full tile covers both orderings; mask i==j; rows only
        for (int nt = 0; nt < NT; nt++) {
            MFMA_TILE
            const int j = j0 + jb + mrow;
            #pragma unroll
            for (int mt = 0; mt < 2; mt++)
                #pragma unroll
                for (int r = 0; r < 4; r++) {
                    int i = I0 + mt * 16 + kq * 4 + r;
                    float d2 = fmaf(-2.0f, acc[mt][r], sqi[mt][r] + sqj);
                    float e2 = exp2f(fmaf(c1, __builtin_amdgcn_sqrtf(d2), SHIFT));
                    e2 = (i != j) ? e2 : 0.0f;     // also kills sqrt(-eps) NaN
                    float tsel = (yj == yi[mt][r]) ? e2 : 0.0f;
                    bs[mt][r] += e2;
                    ts[mt][r] += tsel;
                }
        }
    } else {
        // off-diagonal: i != j guaranteed; scatter to rows AND columns
        for (int nt = 0; nt < NT; nt++) {
            MFMA_TILE
            float colb = 0.0f, colt = 0.0f;
            #pragma unroll
            for (int mt = 0; mt < 2; mt++)
                #pragma unroll
                for (int r = 0; r < 4; r++) {
                    float d2 = fmaf(-2.0f, acc[mt][r], sqi[mt][r] + sqj);
                    float e2 = exp2f(fmaf(c1, __builtin_amdgcn_sqrtf(d2), SHIFT));
                    float tsel = (yj == yi[mt][r]) ? e2 : 0.0f;
                    bs[mt][r] += e2;   ts[mt][r] += tsel;
                    colb += e2;        colt += tsel;
                }
            colb += __shfl_xor(colb, 16, 64); colb += __shfl_xor(colb, 32, 64);
            colt += __shfl_xor(colt, 16, 64); colt += __shfl_xor(colt, 32, 64);
            if (kq == 0) {
                atomicAdd(&s_cb[jb + mrow], colb);
                atomicAdd(&s_ct[jb + mrow], colt);
            }
        }
    }
#undef MFMA_TILE

    // row sums: reduce over the 16 mrow-lanes sharing each row
    #pragma unroll
    for (int mt = 0; mt < 2; mt++)
        #pragma unroll
        for (int r = 0; r < 4; r++) {
            float tv = ts[mt][r], bv = bs[mt][r];
            #pragma unroll
            for (int off = 1; off < 16; off <<= 1) {
                tv += __shfl_xor(tv, off, 64);
                bv += __shfl_xor(bv, off, 64);
            }
            if (mrow == 0) {
                int i = I0 + mt * 16 + kq * 4 + r;
                atomicAdd(&top[i], tv);
                atomicAdd(&bot[i], bv);
            }
        }

    if (bi != bj) {
        __syncthreads();
        if (tid < CH) {
            atomicAdd(&top[j0 + tid], s_ct[tid]);
            atomicAdd(&bot[j0 + tid], s_cb[tid]);
        }
    }

    // arrival counter: last block does the final reduction
    __syncthreads();
    if (tid == 0) {
        __threadfence();
        s_last = (atomicAdd(counter, 1) == NPAIRS - 1);
    }
    __syncthreads();
    if (s_last) {
        float acc = 0.0f;
        for (int i = tid; i < N_ROWS; i += 256) {
            float t = __hip_atomic_load(&top[i], __ATOMIC_RELAXED, __HIP_MEMORY_SCOPE_AGENT);
            float b = __hip_atomic_load(&bot[i], __ATOMIC_RELAXED, __HIP_MEMORY_SCOPE_AGENT);
            acc += (logf(t) - SHIFT_LN) - logf(b * 0x1p-96f + EPS);
        }
        #pragma unroll
        for (int off = 32; off > 0; off >>= 1) acc += __shfl_xor(acc, off, 64);
        if (lane == 0) s_red[wv] = acc;
        __syncthreads();
        if (tid == 0)
            out[0] = -(s_red[0] + s_red[1] + s_red[2] + s_red[3]) / (float)N_ROWS;
    }
}

extern "C" void kernel_launch(void* const* d_in, const int* in_sizes, int n_in,
                              void* d_out, int out_size, void* d_ws, size_t ws_size,
                              hipStream_t stream) {
    const float* x = (const float*)d_in[0];
    const int*   y = (const int*)d_in[1];
    const float* w = (const float*)d_in[2];
    float* out = (float*)d_out;

    float* ws  = (float*)d_ws;
    float* top = ws;
    float* bot = ws + N_ROWS;
    float* sq  = ws + 2 * N_ROWS;
    _Float16* xh = (_Float16*)(ws + 3 * N_ROWS);
    _Float16* xl = xh + (size_t)N_ROWS * DIM;
    int* counter = (int*)(xl + (size_t)N_ROWS * DIM);

    snn_prep<<<N_ROWS / 64, 256, 0, stream>>>(x, xh, xl, sq, top, bot, out, counter);
    snn_sym<<<NPAIRS, 256, 0, stream>>>(xh, xl, sq, y, w, top, bot, counter, out);
}

// Round 8
// 123.333 us; speedup vs baseline: 1.3120x; 1.3120x over previous
//
#include <hip/hip_runtime.h>

typedef _Float16 f16x8 __attribute__((ext_vector_type(8)));
typedef float    f32x4 __attribute__((ext_vector_type(4)));

#define N_ROWS 8192
#define DIM 64
#define EPS 1e-8f
#define LOG2E 1.4426950408889634f
#define SHIFT 96.0f                      // exp terms scaled by 2^96
#define SHIFT_LN 66.54212933375474f      // 96 * ln(2)
#define CH 256                           // chunk (block tile) size
#define NCH (N_ROWS / CH)                // 32
#define NPAIRS (NCH * (NCH + 1) / 2)     // 528
#define NT (CH / 16)                     // 16 j-tiles per block

// ws: top[8192] | bot[8192] | sq[8192] (f32) | xh[8192*64] | xl[8192*64] (f16) | counter (int)

__global__ __launch_bounds__(256) void snn_prep(
    const float* __restrict__ x, _Float16* __restrict__ xh,
    _Float16* __restrict__ xl, float* __restrict__ sq,
    float* __restrict__ top, float* __restrict__ bot,
    float* __restrict__ out, int* __restrict__ counter)
{
    const int tid = threadIdx.x;
    const int gt = blockIdx.x * 256 + tid;
    if (gt < N_ROWS) { top[gt] = 0.0f; bot[gt] = 0.0f; }
    if (gt == 0) { out[0] = 0.0f; counter[0] = 0; }

    const int row = blockIdx.x * 64 + (tid >> 2);
    const int seg = tid & 3;                      // 16 floats per segment
    const float4* xb = (const float4*)(x + row * DIM + seg * 16);
    float4 v0 = xb[0], v1 = xb[1], v2 = xb[2], v3 = xb[3];
    f16x8 h0, h1, l0, l1;
    float s = 0.0f;
#define CV(H, L, o, val) { float vv = (val); _Float16 hh = (_Float16)vv; \
                           H[o] = hh; L[o] = (_Float16)(vv - (float)hh); s += vv * vv; }
    CV(h0, l0, 0, v0.x) CV(h0, l0, 1, v0.y) CV(h0, l0, 2, v0.z) CV(h0, l0, 3, v0.w)
    CV(h0, l0, 4, v1.x) CV(h0, l0, 5, v1.y) CV(h0, l0, 6, v1.z) CV(h0, l0, 7, v1.w)
    CV(h1, l1, 0, v2.x) CV(h1, l1, 1, v2.y) CV(h1, l1, 2, v2.z) CV(h1, l1, 3, v2.w)
    CV(h1, l1, 4, v3.x) CV(h1, l1, 5, v3.y) CV(h1, l1, 6, v3.z) CV(h1, l1, 7, v3.w)
#undef CV
    *(f16x8*)(xh + row * DIM + seg * 16)     = h0;
    *(f16x8*)(xh + row * DIM + seg * 16 + 8) = h1;
    *(f16x8*)(xl + row * DIM + seg * 16)     = l0;
    *(f16x8*)(xl + row * DIM + seg * 16 + 8) = l1;
    s += __shfl_xor(s, 1, 64);
    s += __shfl_xor(s, 2, 64);
    if (seg == 0) sq[row] = s;
}

// symmetric pair-block kernel: chunk pairs (bi <= bj), 256x256 tile per block
// (528 blocks — R7's 128-tile/2080-block version was prologue-latency-bound).
// Rows: register accumulators. Columns (bi<bj): per-wave LDS buffers, no atomics.
__global__ __launch_bounds__(256, 2) void snn_sym(
    const _Float16* __restrict__ xh, const _Float16* __restrict__ xl,
    const float* __restrict__ sq, const int* __restrict__ y,
    const float* __restrict__ w,
    float* __restrict__ top, float* __restrict__ bot,
    int* __restrict__ counter, float* __restrict__ out)
{
    __shared__ float s_sq[CH]; __shared__ int s_y[CH];
    __shared__ float s_ct[4][CH], s_cb[4][CH];
    __shared__ float s_red[4];
    __shared__ int s_last;

    int idx = blockIdx.x, bi = 0;
    while (idx >= NCH - bi) { idx -= NCH - bi; bi++; }
    const int bj = bi + idx;

    const int tid = threadIdx.x, wv = tid >> 6, lane = tid & 63;
    const int mrow = lane & 15, kq = lane >> 4;
    const int I0 = bi * CH + wv * 64;     // this wave's 64 i-rows
    const int j0 = bj * CH;

    s_sq[tid] = sq[j0 + tid];
    s_y[tid]  = y[j0 + tid];
    #pragma unroll
    for (int c = lane; c < CH; c += 64) { s_ct[wv][c] = 0.0f; s_cb[wv][c] = 0.0f; }
    __syncthreads();

    // A fragments resident (4 m-tiles x 2 k-chunks, hi/lo): 64 VGPRs
    f16x8 ah[4][2], al[4][2];
    #pragma unroll
    for (int mt = 0; mt < 4; mt++)
        #pragma unroll
        for (int kc = 0; kc < 2; kc++) {
            int a = (I0 + mt * 16 + mrow) * DIM + kc * 32 + kq * 8;
            ah[mt][kc] = *(const f16x8*)(xh + a);
            al[mt][kc] = *(const f16x8*)(xl + a);
        }

    float sqi[4][4]; int ypack[4];
    #pragma unroll
    for (int mt = 0; mt < 4; mt++) {
        int yp = 0;
        #pragma unroll
        for (int r = 0; r < 4; r++) {
            int i = I0 + mt * 16 + kq * 4 + r;
            sqi[mt][r] = sq[i];
            yp |= (y[i] & 255) << (8 * r);
        }
        ypack[mt] = yp;
    }

    float ts[4][4], bs[4][4];
    #pragma unroll
    for (int mt = 0; mt < 4; mt++)
        #pragma unroll
        for (int r = 0; r < 4; r++) { ts[mt][r] = 0.0f; bs[mt][r] = 0.0f; }

    const float c1 = -w[0] * LOG2E;

#define MFMA_TILE                                                                          \
    const int jb = nt * 16;                                                                \
    const int bbase = (j0 + jb + mrow) * DIM + kq * 8;                                     \
    f16x8 bh0 = *(const f16x8*)(xh + bbase);                                               \
    f16x8 bh1 = *(const f16x8*)(xh + bbase + 32);                                          \
    f16x8 bl0 = *(const f16x8*)(xl + bbase);                                               \
    f16x8 bl1 = *(const f16x8*)(xl + bbase + 32);                                          \
    const float sqj = s_sq[jb + mrow];                                                     \
    const int   yj  = s_y[jb + mrow];                                                      \
    f32x4 acc[4];                                                                          \
    acc[0] = (f32x4){0.f, 0.f, 0.f, 0.f}; acc[1] = acc[0]; acc[2] = acc[0]; acc[3] = acc[0]; \
    _Pragma("unroll") for (int mt = 0; mt < 4; mt++)                                       \
        acc[mt] = __builtin_amdgcn_mfma_f32_16x16x32_f16(ah[mt][0], bh0, acc[mt], 0,0,0);  \
    _Pragma("unroll") for (int mt = 0; mt < 4; mt++)                                       \
        acc[mt] = __builtin_amdgcn_mfma_f32_16x16x32_f16(ah[mt][1], bh1, acc[mt], 0,0,0);  \
    _Pragma("unroll") for (int mt = 0; mt < 4; mt++)                                       \
        acc[mt] = __builtin_amdgcn_mfma_f32_16x16x32_f16(ah[mt][0], bl0, acc[mt], 0,0,0);  \
    _Pragma("unroll") for (int mt = 0; mt < 4; mt++)                                       \
        acc[mt] = __builtin_amdgcn_mfma_f32_16x16x32_f16(ah[mt][1], bl1, acc[mt], 0,0,0);  \
    _Pragma("unroll") for (int mt = 0; mt < 4; mt++)                                       \
        acc[mt] = __builtin_amdgcn_mfma_f32_16x16x32_f16(al[mt][0], bh0, acc[mt], 0,0,0);  \
    _Pragma("unroll") for (int mt = 0; mt < 4; mt++)                                       \
        acc[mt] = __builtin_amdgcn_mfma_f32_16x16x32_f16(al[mt][1], bh1, acc[mt], 0,0,0);

    if (bi == bj) {
        // diagonal chunk: full tile covers both orderings; mask i==j; rows only
        for (int nt = 0; nt < NT; nt++) {
            MFMA_TILE
            const int j = j0 + jb + mrow;
            #pragma unroll
            for (int mt = 0; mt < 4; mt++)
                #pragma unroll
                for (int r = 0; r < 4; r++) {
                    int i = I0 + mt * 16 + kq * 4 + r;
                    float d2 = fmaf(-2.0f, acc[mt][r], sqi[mt][r] + sqj);
                    float e2 = exp2f(fmaf(c1, __builtin_amdgcn_sqrtf(d2), SHIFT));
                    e2 = (i != j) ? e2 : 0.0f;     // also kills sqrt(-eps) NaN
                    float tsel = (yj == ((ypack[mt] >> (8 * r)) & 255)) ? e2 : 0.0f;
                    bs[mt][r] += e2;
                    ts[mt][r] += tsel;
                }
        }
    } else {
        // off-diagonal: i != j guaranteed; scatter to rows AND columns
        for (int nt = 0; nt < NT; nt++) {
            MFMA_TILE
            float colb = 0.0f, colt = 0.0f;
            #pragma unroll
            for (int mt = 0; mt < 4; mt++)
                #pragma unroll
                for (int r = 0; r < 4; r++) {
                    float d2 = fmaf(-2.0f, acc[mt][r], sqi[mt][r] + sqj);
                    float e2 = exp2f(fmaf(c1, __builtin_amdgcn_sqrtf(d2), SHIFT));
                    float tsel = (yj == ((ypack[mt] >> (8 * r)) & 255)) ? e2 : 0.0f;
                    bs[mt][r] += e2;   ts[mt][r] += tsel;
                    colb += e2;        colt += tsel;
                }
            colb += __shfl_xor(colb, 16, 64); colb += __shfl_xor(colb, 32, 64);
            colt += __shfl_xor(colt, 16, 64); colt += __shfl_xor(colt, 32, 64);
            if (kq == 0) {                     // 16 lanes, distinct cols, own wave buffer
                s_cb[wv][jb + mrow] += colb;
                s_ct[wv][jb + mrow] += colt;
            }
        }
    }
#undef MFMA_TILE

    // row sums: reduce over the 16 mrow-lanes sharing each row
    #pragma unroll
    for (int mt = 0; mt < 4; mt++)
        #pragma unroll
        for (int r = 0; r < 4; r++) {
            float tv = ts[mt][r], bv = bs[mt][r];
            #pragma unroll
            for (int off = 1; off < 16; off <<= 1) {
                tv += __shfl_xor(tv, off, 64);
                bv += __shfl_xor(bv, off, 64);
            }
            if (mrow == 0) {
                int i = I0 + mt * 16 + kq * 4 + r;
                atomicAdd(&top[i], tv);
                atomicAdd(&bot[i], bv);
            }
        }

    if (bi != bj) {
        __syncthreads();
        float ct = s_ct[0][tid] + s_ct[1][tid] + s_ct[2][tid] + s_ct[3][tid];
        float cb = s_cb[0][tid] + s_cb[1][tid] + s_cb[2][tid] + s_cb[3][tid];
        atomicAdd(&top[j0 + tid], ct);
        atomicAdd(&bot[j0 + tid], cb);
    }

    // arrival counter: last block performs the final log-reduction
    __syncthreads();
    if (tid == 0) {
        __threadfence();
        s_last = (atomicAdd(counter, 1) == NPAIRS - 1);
    }
    __syncthreads();
    if (s_last) {
        float acc = 0.0f;
        for (int i = tid; i < N_ROWS; i += 256) {
            float t = __hip_atomic_load(&top[i], __ATOMIC_RELAXED, __HIP_MEMORY_SCOPE_AGENT);
            float b = __hip_atomic_load(&bot[i], __ATOMIC_RELAXED, __HIP_MEMORY_SCOPE_AGENT);
            acc += (logf(t) - SHIFT_LN) - logf(b * 0x1p-96f + EPS);
        }
        #pragma unroll
        for (int off = 32; off > 0; off >>= 1) acc += __shfl_xor(acc, off, 64);
        if (lane == 0) s_red[wv] = acc;
        __syncthreads();
        if (tid == 0)
            out[0] = -(s_red[0] + s_red[1] + s_red[2] + s_red[3]) / (float)N_ROWS;
    }
}

extern "C" void kernel_launch(void* const* d_in, const int* in_sizes, int n_in,
                              void* d_out, int out_size, void* d_ws, size_t ws_size,
                              hipStream_t stream) {
    const float* x = (const float*)d_in[0];
    const int*   y = (const int*)d_in[1];
    const float* w = (const float*)d_in[2];
    float* out = (float*)d_out;

    float* ws  = (float*)d_ws;
    float* top = ws;
    float* bot = ws + N_ROWS;
    float* sq  = ws + 2 * N_ROWS;
    _Float16* xh = (_Float16*)(ws + 3 * N_ROWS);
    _Float16* xl = xh + (size_t)N_ROWS * DIM;
    int* counter = (int*)(xl + (size_t)N_ROWS * DIM);

    snn_prep<<<N_ROWS / 64, 256, 0, stream>>>(x, xh, xl, sq, top, bot, out, counter);
    snn_sym<<<NPAIRS, 256, 0, stream>>>(xh, xl, sq, y, w, top, bot, counter, out);
}